// Round 6
// baseline (151.793 us; speedup 1.0000x reference)
//
#include <hip/hip_runtime.h>
#include <hip/hip_cooperative_groups.h>

namespace cg = cooperative_groups;

// StericClashConstraint: N=16384 pts [N,3] fp32.
// out[0..3N-1] = pos passthrough; out[3N] = mean(max(1-dist,0), diag=0) * 0.02
//
// Round 12: SINGLE COOPERATIVE DISPATCH. R11 counters: harness ws-poison fill
// is 39.5us (fixed floor); our 4 kernels sum to ~12-15us of device time but
// ~52us of wall -> ~8us serialized cost per graph node. Fix: fuse the whole
// pipeline into one 256-block cooperative kernel (1 block/CU, co-residency
// guaranteed) with 2 grid.sync()s:
//   A: blocks 0..63: passthrough copy + per-block LDS z-histogram; keep
//      {x,y,z,cell,rank} in registers (rank = LDS-atomic return value).
//   [sync]  B: EVERY block redundantly scans the 64x256 partials (coalesced
//      L2 reads + Hillis-Steele in LDS) -> no block-0 serialization, no global
//      cursor, no jend array. Scatter dst = excl[cell]+before_blk[cell]+rank
//      (no global atomics). Each block binary-searches its group's jend into
//      a register.
//   [sync]  C: R11 pair body (bit-identical per-pair math) + acc/cnt finalize.
// Bins: 256 x width 1/4 (z*4 exact in fp32), MARGIN=6 -> excluded pairs have
// dz > 1.25 exactly; clamped edge bins only widen windows (conservative).
// Cross-phase visibility: writer __threadfence() + grid.sync() acq/rel
// (agent-scope fences: L2 writeback/invalidate across XCDs).

constexpr int   N     = 16384;
constexpr int   BLOCK = 256;            // 4 waves
constexpr int   GSZ   = 512;            // i-group size
constexpr int   IPT   = GSZ / BLOCK;    // 2 i's per thread
constexpr int   NG    = N / GSZ;        // 32 i-groups
constexpr int   F     = 8;              // j-segments per group
constexpr int   NB    = NG * F;         // 256 blocks = 1/CU (co-resident)
constexpr int   QB    = 4;              // columns per unrolled chunk
constexpr int   NBINS = 256;            // z-bins, width 1/4, covering [-32,32)
constexpr float BINW_INV = 4.0f;        // *4 is exact in fp32
constexpr int   MARGIN = 6;             // cell_j >= cell_last+6 => dz > 1.25 > 1
constexpr int   CH    = 288;            // columns staged per LDS chunk
constexpr int   NHB   = N / BLOCK;      // 64 blocks own the 16384 points

__device__ __forceinline__ int zcell(float z) {
    int c = (int)floorf(z * BINW_INV) + NBINS / 2;
    return min(max(c, 0), NBINS - 1);
}

template <bool MASKED>
__device__ __forceinline__ float cols(const float4* __restrict__ jsm,
                                      int clen, int jbase, int i0,
                                      const float (&xi2)[IPT], const float (&yi2)[IPT],
                                      const float (&zi2)[IPT], const float (&sqi)[IPT]) {
    float s = 0.0f;
    for (int c = 0; c < clen; c += QB) {              // sentinel pad covers overrun
        #pragma unroll
        for (int u = 0; u < QB; ++u) {
            const float4 pj = jsm[c + u];             // uniform addr -> broadcast
            const int jq = jbase + c + u;
            #pragma unroll
            for (int k = 0; k < IPT; ++k) {
                float d = fmaf(xi2[k], pj.x, pj.w);
                d = fmaf(yi2[k], pj.y, d);
                d = fmaf(zi2[k], pj.z, d);                     // sq_j - 2*dot
                const float d2 = fmaxf(d + sqi[k], 0.0f);      // + sq_i, clamp
                float w = 1.0f - __builtin_amdgcn_sqrtf(d2);   // 1 - dist
                w = fmaxf(w, 0.0f);                            // clamp(min=0)
                if (MASKED) w = (jq > i0 + k * BLOCK) ? w : 0.0f;   // j>i only
                s += w;
            }
        }
    }
    return s;
}

__global__ void __launch_bounds__(BLOCK)
fused_kernel(const float* __restrict__ pos, float* __restrict__ out,
             unsigned int* __restrict__ histPart, float4* __restrict__ jt4s,
             float* __restrict__ acc, unsigned int* __restrict__ cnt) {
    __shared__ unsigned int lh[NBINS];
    __shared__ int sm[NBINS];
    __shared__ int beforeB[NBINS];
    __shared__ float4 jsm[CH + QB];
    __shared__ float wsum[BLOCK / 64];

    const cg::grid_group grid = cg::this_grid();
    const int b = blockIdx.x;
    const int t = threadIdx.x;
    const int gt = b * BLOCK + t;

    // ---- phase A: copy + per-block histogram (blocks 0..63 own the points) --
    float px = 0.0f, py = 0.0f, pz = 0.0f;
    int cell = 0;
    unsigned int rank = 0u;
    if (b < NHB) {
        lh[t] = 0u;
        if (gt == 0) { atomicExch(acc, 0.0f); atomicExch(cnt, 0u); }
        __syncthreads();
        if (gt < (N * 3) / 4) {
            reinterpret_cast<float4*>(out)[gt] =
                reinterpret_cast<const float4*>(pos)[gt];
        }
        px = pos[3 * gt]; py = pos[3 * gt + 1]; pz = pos[3 * gt + 2];
        cell = zcell(pz);
        rank = atomicAdd(&lh[cell], 1u);              // rank within block & bin
        __syncthreads();
        histPart[b * NBINS + t] = lh[t];
        __threadfence();
    }
    grid.sync();

    // ---- phase B: every block redundantly scans the partials ---------------
    {
        int v = 0, bef = 0;
        for (int p = 0; p < NHB; ++p) {               // coalesced L2 reads
            const int hv = (int)histPart[p * NBINS + t];
            if (p == b) bef = v;                      // sum over blocks < b
            v += hv;
        }
        sm[t] = v; beforeB[t] = bef;
    }
    __syncthreads();
    for (int off = 1; off < NBINS; off <<= 1) {       // Hillis-Steele inclusive
        const int a = (t >= off) ? sm[t - off] : 0;
        __syncthreads();
        sm[t] += a;
        __syncthreads();
    }
    // scatter (no global atomics): dst = excl[cell] + before_block[cell] + rank
    if (b < NHB) {
        const int ex = (cell > 0) ? sm[cell - 1] : 0;
        const unsigned int dst = (unsigned int)(ex + beforeB[cell]) + rank;
        jt4s[dst] = make_float4(px, py, pz, fmaf(px, px, fmaf(py, py, pz * pz)));
        __threadfence();
    }
    // every block: its group's j-window end (register, no global array)
    const int g = b >> 3, f = b & (F - 1);
    int jend;
    {
        const int p = (g + 1) * GSZ - 1;              // last sorted idx of group
        int lo = 0, hi = NBINS - 1;
        while (lo < hi) {                             // smallest c: incl[c] >= p+1
            const int mid = (lo + hi) >> 1;
            if (sm[mid] >= p + 1) hi = mid; else lo = mid + 1;
        }
        const int jidx = lo + MARGIN;
        jend = (jidx >= NBINS) ? N : sm[jidx - 1];    // excl[jidx]
    }
    grid.sync();

    // ---- phase C: pruned pair sweep (R11 body) -----------------------------
    const int gstart = g * GSZ;
    const int i0 = gstart + t;
    const float4 w0 = jt4s[i0];
    const float4 w1 = jt4s[i0 + BLOCK];

    const int jbeg = gstart + 1;
    const int jlen = jend - jbeg;                     // >= GSZ-1 always
    const int seg  = (((jlen + F - 1) / F) + QB - 1) & ~(QB - 1);  // QB-aligned
    const int j0   = jbeg + f * seg;
    const int len  = min(seg, jend - j0);             // >0 for all f (jlen>=511)

    float xi2[IPT], yi2[IPT], zi2[IPT], sqi[IPT];
    xi2[0] = -2.0f * w0.x; yi2[0] = -2.0f * w0.y; zi2[0] = -2.0f * w0.z; sqi[0] = w0.w;
    xi2[1] = -2.0f * w1.x; yi2[1] = -2.0f * w1.y; zi2[1] = -2.0f * w1.z; sqi[1] = w1.w;

    float s = 0.0f;
    for (int cs = 0; cs < len; cs += CH) {
        const int clen = min(CH, len - cs);
        if (t < clen)         jsm[t]         = jt4s[j0 + cs + t];
        if (t + BLOCK < clen) jsm[t + BLOCK] = jt4s[j0 + cs + t + BLOCK];
        if (t < QB) jsm[max(clen, 0) + t] = make_float4(0.0f, 0.0f, 1.0e6f, 4.0e12f);
        __syncthreads();
        if (j0 + cs < gstart + GSZ)    // chunk may overlap own group: j>i mask
            s += cols<true >(jsm, clen, j0 + cs, i0, xi2, yi2, zi2, sqi);
        else
            s += cols<false>(jsm, clen, j0 + cs, i0, xi2, yi2, zi2, sqi);
        __syncthreads();               // before next chunk overwrites jsm
    }

    // reduce: wave shuffle -> LDS -> one atomic per block
    for (int off = 32; off > 0; off >>= 1) s += __shfl_down(s, off);
    if ((t & 63) == 0) wsum[t >> 6] = s;
    __syncthreads();
    if (t == 0) {
        float bs = 0.0f;
        #pragma unroll
        for (int w = 0; w < BLOCK / 64; ++w) bs += wsum[w];
        atomicAdd(acc, bs);
        __threadfence();
        const unsigned int done = atomicAdd(cnt, 1u);
        if (done == (unsigned int)(NB - 1)) {          // last block finalizes
            __threadfence();
            const float total = atomicAdd(acc, 0.0f);  // device-coherent read
            const double mean = 2.0 * (double)total / ((double)N * (double)N);
            out[(size_t)N * 3] = (float)(mean * 0.02);
        }
    }
}

extern "C" void kernel_launch(void* const* d_in, const int* in_sizes, int n_in,
                              void* d_out, int out_size, void* d_ws, size_t ws_size,
                              hipStream_t stream) {
    const float* pos = (const float*)d_in[0];
    float* out = (float*)d_out;
    // ws layout:
    //   0:      acc (float)      4: cnt (uint)
    //   4096:   histPart[64][256]  (64 KiB)
    //   131072: jt4s[N x float4]   (256 KiB)
    float*        acc      = (float*)d_ws;
    unsigned int* cnt      = (unsigned int*)d_ws + 1;
    unsigned int* histPart = (unsigned int*)((char*)d_ws + 4096);
    float4*       jt4s     = (float4*)((char*)d_ws + 131072);

    void* args[] = { (void*)&pos, (void*)&out, (void*)&histPart,
                     (void*)&jt4s, (void*)&acc, (void*)&cnt };
    hipLaunchCooperativeKernel((void (*)(const float*, float*, unsigned int*,
                                         float4*, float*, unsigned int*))fused_kernel,
                               dim3(NB), dim3(BLOCK), args, 0, stream);
}

// Round 7
// 81.999 us; speedup vs baseline: 1.8512x; 1.8512x over previous
//
#include <hip/hip_runtime.h>

// StericClashConstraint: N=16384 pts [N,3] fp32.
// out[0..3N-1] = pos passthrough; out[3N] = mean(max(1-dist,0), diag=0) * 0.02
//
// Round 13: 3 dispatches, NO in-kernel grid sync.
// R12 post-mortem: cg::grid_group::sync() costs ~35us EACH on 256 blocks
// (fused kernel 85us wall, 7.7us VALU work) - cooperative barrier spin +
// system-scope fences across 8 non-coherent XCDs. Kernel boundaries are the
// only cheap grid-wide syncs. The algorithm needs exactly two: hist->scatter
// and scatter->pair. So:
//  k1 prep:    copy + per-block LDS z-hist -> partials; pack each point's
//              (cell, in-block rank) into crk[] (rank = LDS-atomic return);
//              zero acc/cnt (replaces memset dispatch).
//  k2 scatter: 64 blocks EACH redundantly reduce the 64x256 partials
//              (coalesced L2) + Hillis-Steele scan in LDS (R12 phase B, proven
//              absmax=0), then dst = excl[cell]+before_blk[cell]+rank -> NO
//              global atomics. Block 0 binary-searches jendArr (R11-identical).
//  k3 pair:    R11 pair kernel verbatim (256 fat blocks = 1/CU, LDS-staged
//              j-chunks, branchless per-pair math, bit-identical to R8..R12).
// Bins: 256 x width 1/4 (z*4 exact in fp32), MARGIN=6 -> excluded pairs have
// dz > 1.25 > 1 exactly (clamped edge bins only widen windows; conservative).

constexpr int   N     = 16384;
constexpr int   BLOCK = 256;            // 4 waves
constexpr int   GSZ   = 512;            // i-group size
constexpr int   IPT   = GSZ / BLOCK;    // 2 i's per thread
constexpr int   NG    = N / GSZ;        // 32 i-groups
constexpr int   F     = 8;              // j-segments per group
constexpr int   NB    = NG * F;         // 256 pair blocks = 1/CU
constexpr int   QB    = 4;              // columns per unrolled chunk
constexpr int   NBINS = 256;            // z-bins, width 1/4, covering [-32,32)
constexpr float BINW_INV = 4.0f;        // *4 exact in fp32
constexpr int   MARGIN = 6;             // cell_j >= cell_i+6 => dz > 1.25 > 1
constexpr int   CH    = 288;            // columns staged per LDS chunk
constexpr int   NHB   = N / BLOCK;      // 64 blocks own the points

__device__ __forceinline__ int zcell(float z) {
    int c = (int)floorf(z * BINW_INV) + NBINS / 2;
    return min(max(c, 0), NBINS - 1);
}

// ---- k1: passthrough + per-block partial hist + (cell,rank) pack -----------
__global__ void __launch_bounds__(BLOCK)
prep_kernel(const float* __restrict__ pos, float* __restrict__ out,
            unsigned int* __restrict__ histPart, unsigned int* __restrict__ crk,
            float* __restrict__ acc, unsigned int* __restrict__ cnt) {
    __shared__ unsigned int lh[NBINS];
    const int b = blockIdx.x, t = threadIdx.x;
    const int gt = b * BLOCK + t;                     // 0..16383
    lh[t] = 0u;                                       // NBINS == BLOCK
    if (gt == 0) { *acc = 0.0f; *cnt = 0u; }          // replaces memset dispatch
    __syncthreads();
    if (gt < (N * 3) / 4) {
        reinterpret_cast<float4*>(out)[gt] = reinterpret_cast<const float4*>(pos)[gt];
    }
    const float z = pos[3 * gt + 2];
    const int cell = zcell(z);
    const unsigned int rank = atomicAdd(&lh[cell], 1u);   // rank in (block,cell)
    crk[gt] = (unsigned int)cell | (rank << 16);
    __syncthreads();
    histPart[b * NBINS + t] = lh[t];
}

// ---- k2: redundant scan per block + atomic-free scatter + jendArr ----------
__global__ void __launch_bounds__(BLOCK)
scatter_kernel(const float* __restrict__ pos, const unsigned int* __restrict__ histPart,
               const unsigned int* __restrict__ crk, float4* __restrict__ jt4s,
               int* __restrict__ jendArr) {
    __shared__ int sm[NBINS];
    __shared__ int beforeB[NBINS];
    const int b = blockIdx.x, t = threadIdx.x;        // 64 blocks x 256
    int v = 0, bef = 0;
    #pragma unroll 8
    for (int p = 0; p < NHB; ++p) {                   // coalesced L2 reads
        const int hv = (int)histPart[p * NBINS + t];
        if (p == b) bef = v;                          // sum over blocks < b
        v += hv;
    }
    sm[t] = v; beforeB[t] = bef;
    __syncthreads();
    for (int off = 1; off < NBINS; off <<= 1) {       // Hillis-Steele inclusive
        const int a = (t >= off) ? sm[t - off] : 0;
        __syncthreads();
        sm[t] += a;
        __syncthreads();
    }
    // scatter own 256 points, no atomics
    const int gt = b * BLOCK + t;
    const unsigned int cr = crk[gt];
    const int cell = (int)(cr & 0xffffu);
    const int rank = (int)(cr >> 16);
    const int ex   = (cell > 0) ? sm[cell - 1] : 0;
    const int dst  = ex + beforeB[cell] + rank;
    const float x = pos[3 * gt], y = pos[3 * gt + 1], z = pos[3 * gt + 2];
    jt4s[dst] = make_float4(x, y, z, fmaf(x, x, fmaf(y, y, z * z)));
    // block 0: per-group j-window ends (identical to R11 scan_kernel)
    if (b == 0 && t < NG) {
        const int p = (t + 1) * GSZ - 1;              // last sorted idx of group
        int lo = 0, hi = NBINS - 1;
        while (lo < hi) {                             // smallest c: incl[c] >= p+1
            const int mid = (lo + hi) >> 1;
            if (sm[mid] >= p + 1) hi = mid; else lo = mid + 1;
        }
        const int jidx = lo + MARGIN;
        jendArr[t] = (jidx >= NBINS) ? N : sm[jidx - 1];   // excl[jidx]
    }
}

// ---- k3: pruned pair sweep (R11 verbatim) ----------------------------------
template <bool MASKED>
__device__ __forceinline__ float cols(const float4* __restrict__ jsm,
                                      int clen, int jbase, int i0,
                                      const float (&xi2)[IPT], const float (&yi2)[IPT],
                                      const float (&zi2)[IPT], const float (&sqi)[IPT]) {
    float s = 0.0f;
    for (int c = 0; c < clen; c += QB) {              // sentinel pad covers overrun
        #pragma unroll
        for (int u = 0; u < QB; ++u) {
            const float4 pj = jsm[c + u];             // uniform addr -> broadcast
            const int jq = jbase + c + u;
            #pragma unroll
            for (int k = 0; k < IPT; ++k) {
                float d = fmaf(xi2[k], pj.x, pj.w);
                d = fmaf(yi2[k], pj.y, d);
                d = fmaf(zi2[k], pj.z, d);                     // sq_j - 2*dot
                const float d2 = fmaxf(d + sqi[k], 0.0f);      // + sq_i, clamp
                float w = 1.0f - __builtin_amdgcn_sqrtf(d2);   // 1 - dist
                w = fmaxf(w, 0.0f);                            // clamp(min=0)
                if (MASKED) w = (jq > i0 + k * BLOCK) ? w : 0.0f;   // j>i only
                s += w;
            }
        }
    }
    return s;
}

__global__ void __launch_bounds__(BLOCK)
pair_kernel(const float4* __restrict__ jt4s, const int* __restrict__ jendArr,
            float* __restrict__ out, float* __restrict__ acc,
            unsigned int* __restrict__ cnt) {
    __shared__ float4 jsm[CH + QB];
    __shared__ float wsum[BLOCK / 64];
    const int b = blockIdx.x;
    const int t = threadIdx.x;
    const int g = b >> 3, f = b & (F - 1);
    const int gstart = g * GSZ;
    const int i0 = gstart + t;

    // issue i-fragment loads first (overlap with jend load + param math)
    const float4 w0 = jt4s[i0];
    const float4 w1 = jt4s[i0 + BLOCK];

    const int jend = jendArr[g];                       // one scalar load
    const int jbeg = gstart + 1;
    const int jlen = jend - jbeg;                      // >= GSZ-1 always
    const int seg  = (((jlen + F - 1) / F) + QB - 1) & ~(QB - 1);  // QB-aligned
    const int j0   = jbeg + f * seg;
    const int len  = min(seg, jend - j0);              // > 0 for all f (jlen>=511)

    float xi2[IPT], yi2[IPT], zi2[IPT], sqi[IPT];
    xi2[0] = -2.0f * w0.x; yi2[0] = -2.0f * w0.y; zi2[0] = -2.0f * w0.z; sqi[0] = w0.w;
    xi2[1] = -2.0f * w1.x; yi2[1] = -2.0f * w1.y; zi2[1] = -2.0f * w1.z; sqi[1] = w1.w;

    float s = 0.0f;
    for (int cs = 0; cs < len; cs += CH) {             // 1 chunk for typical data
        const int clen = min(CH, len - cs);
        if (t < clen)         jsm[t]         = jt4s[j0 + cs + t];
        if (t + BLOCK < clen) jsm[t + BLOCK] = jt4s[j0 + cs + t + BLOCK];
        if (t < QB) jsm[clen + t] = make_float4(0.0f, 0.0f, 1.0e6f, 4.0e12f);
        __syncthreads();
        if (j0 + cs < gstart + GSZ)    // chunk may overlap own group: j>i mask
            s += cols<true >(jsm, clen, j0 + cs, i0, xi2, yi2, zi2, sqi);
        else
            s += cols<false>(jsm, clen, j0 + cs, i0, xi2, yi2, zi2, sqi);
        __syncthreads();               // before next chunk overwrites jsm
    }

    // reduce: wave shuffle -> LDS -> one atomic per block
    for (int off = 32; off > 0; off >>= 1) s += __shfl_down(s, off);
    if ((t & 63) == 0) wsum[t >> 6] = s;
    __syncthreads();
    if (t == 0) {
        float bs = 0.0f;
        #pragma unroll
        for (int w = 0; w < BLOCK / 64; ++w) bs += wsum[w];
        atomicAdd(acc, bs);
        __threadfence();
        const unsigned int done = atomicAdd(cnt, 1u);
        if (done == (unsigned int)(NB - 1)) {          // last block finalizes
            __threadfence();
            const float total = atomicAdd(acc, 0.0f);  // device-coherent read
            const double mean = 2.0 * (double)total / ((double)N * (double)N);
            out[(size_t)N * 3] = (float)(mean * 0.02);
        }
    }
}

extern "C" void kernel_launch(void* const* d_in, const int* in_sizes, int n_in,
                              void* d_out, int out_size, void* d_ws, size_t ws_size,
                              hipStream_t stream) {
    const float* pos = (const float*)d_in[0];
    float* out = (float*)d_out;
    // ws layout:
    //   0:      acc (float)      4: cnt (uint)
    //   256:    jendArr[32]          (128 B)
    //   4096:   histPart[64][256]    (64 KiB)   -> ends 69632
    //   69632:  crk[16384] (uint)    (64 KiB)   -> ends 135168
    //   135168: jt4s[N x float4]     (256 KiB)
    float*        acc      = (float*)d_ws;
    unsigned int* cnt      = (unsigned int*)d_ws + 1;
    int*          jendArr  = (int*)((char*)d_ws + 256);
    unsigned int* histPart = (unsigned int*)((char*)d_ws + 4096);
    unsigned int* crk      = (unsigned int*)((char*)d_ws + 69632);
    float4*       jt4s     = (float4*)((char*)d_ws + 135168);

    prep_kernel   <<<NHB, BLOCK, 0, stream>>>(pos, out, histPart, crk, acc, cnt);
    scatter_kernel<<<NHB, BLOCK, 0, stream>>>(pos, histPart, crk, jt4s, jendArr);
    pair_kernel   <<<NB,  BLOCK, 0, stream>>>(jt4s, jendArr, out, acc, cnt);
}